// Round 3
// baseline (12223.064 us; speedup 1.0000x reference)
//
#include <hip/hip_runtime.h>
#include <stdint.h>

// BDH: B=2 T=2048 D=256 H=4 N=32768 Nh=8192 L=6 VOCAB=256
typedef unsigned short u16;
typedef __bf16 bfv8 __attribute__((ext_vector_type(8)));
typedef float f32x4 __attribute__((ext_vector_type(4)));

#define BM 128
#define BN 128
#define BK 32

__device__ __forceinline__ float b2f(u16 u){ union{float f; unsigned int i;} x; x.i = ((unsigned int)u)<<16; return x.f; }
__device__ __forceinline__ u16 f2b(float f){ union{float f; unsigned int i;} x; x.f = f; unsigned int r = x.i + 0x7fffu + ((x.i>>16)&1u); return (u16)(r>>16); }

__device__ __forceinline__ void load16_lds(const void* g, void* l){
  __builtin_amdgcn_global_load_lds(
      (const __attribute__((address_space(1))) void*)g,
      (__attribute__((address_space(3))) void*)l, 16, 0, 0);
}

struct GP {
  const u16* A; const u16* Bt; const u16* ct; const u16* st;
  float* Cf; u16* Cb; u16* Y;
  int bh0;
};

// OP: 0=readout(f32), 1=G1 relu->x, 2=QK mask->sc, 3=PV(f32,kend=diag),
//     5=G2 relu*Y in place, 6=G1+rope->xr, 7=G3 -> part[bh]
template<int OP>
__global__ __launch_bounds__(256) void gemm(GP p){
  const int m0 = blockIdx.y * BM;
  const int z  = blockIdx.z;
  const int bh = p.bh0 + z, b = bh >> 2, h = bh & 3;
  const int n0 = (OP==6) ? (blockIdx.x * 64) : (blockIdx.x * BN);
  if (OP==2 && n0 >= m0 + BM) return;   // strictly above diagonal

  constexpr int lda = (OP==2||OP==7) ? 8192 : (OP==3 ? 2048 : 256);
  constexpr int ldb = (OP==2) ? 8192 : (OP==3 ? 2048 : (OP==7 ? 32768 : 256));
  constexpr int KK  = (OP==2||OP==7) ? 8192 : (OP==3 ? 2048 : 256);

  const u16* A; const u16* Bt;
  if (OP==0){ A = p.A; Bt = p.Bt; }
  else if (OP==1||OP==6){ A = p.A + (long)b*524288; Bt = p.Bt + (long)h*2097152; }
  else if (OP==2){ A = p.A + (long)z*16777216; Bt = A; }
  else if (OP==3){ A = p.A + (long)z*4194304; Bt = p.Bt + (long)b*524288; }
  else if (OP==5){ A = p.A + (long)z*524288; Bt = p.Bt + (long)h*2097152; }
  else { A = p.A + (long)z*16777216; Bt = p.Bt + (long)h*8192; }

  int kend = KK;
  if (OP==3) kend = min(KK, m0 + BM);

  __shared__ u16 As[BM*BK];
  __shared__ u16 Bs[BN*BK];

  const int tid = threadIdx.x;
  const int lane = tid & 63;
  const int wid = tid >> 6;
  const int wm = wid >> 1, wn = wid & 1;
  const int srow = tid >> 2, sslot = tid & 3;

  f32x4 acc[4][4] = {};

  for (int k0 = 0; k0 < kend; k0 += BK){
    #pragma unroll
    for (int q = 0; q < 2; ++q){
      int row = q*64 + srow;
      int ks = sslot ^ ((row >> 1) & 3);           // bank-spread XOR swizzle
      load16_lds(A + (long)(m0 + row) * lda + (k0 + ks*8), As + q*2048 + wid*512);
    }
    #pragma unroll
    for (int q = 0; q < 2; ++q){
      int row = q*64 + srow;
      int ks = sslot ^ ((row >> 1) & 3);
      long brow;
      if (OP==6){   // paired col groups: rows 0..31 low, 32..63 high (per wn half)
        int wnb = row >> 6, sub = (row >> 5) & 1, r5 = row & 31;
        brow = n0 + wnb*32 + r5 + sub*4096;
      } else {
        brow = n0 + row;
      }
      load16_lds(Bt + brow * (long)ldb + (k0 + ks*8), Bs + q*2048 + wid*512);
    }
    __syncthreads();
    bfv8 af[4], bf[4];
    const int r16 = lane & 15, s4 = lane >> 4;
    #pragma unroll
    for (int i = 0; i < 4; ++i){
      int ar = wm*64 + i*16 + r16;
      af[i] = *(const bfv8*)(As + ar*BK + ((s4 ^ ((ar>>1)&3))*8));
      int br = wn*64 + i*16 + r16;
      bf[i] = *(const bfv8*)(Bs + br*BK + ((s4 ^ ((br>>1)&3))*8));
    }
    #pragma unroll
    for (int i = 0; i < 4; ++i)
      #pragma unroll
      for (int j = 0; j < 4; ++j)
        acc[i][j] = __builtin_amdgcn_mfma_f32_16x16x32_bf16(af[i], bf[j], acc[i][j], 0,0,0);
    __syncthreads();
  }

  const int r16 = lane & 15, s4 = lane >> 4;
  if (OP==6){
    #pragma unroll
    for (int i = 0; i < 4; ++i){
      #pragma unroll
      for (int j = 0; j < 2; ++j){
        int cl = n0 + wn*32 + j*16 + r16;          // low col in [0,4096)
        #pragma unroll
        for (int v = 0; v < 4; ++v){
          int row = m0 + wm*64 + i*16 + s4*4 + v;
          float x1 = fmaxf(acc[i][j][v], 0.f);
          float x2 = fmaxf(acc[i][j+2][v], 0.f);
          float c = b2f(p.ct[(long)row*4096 + cl]);
          float s = b2f(p.st[(long)row*4096 + cl]);
          p.Cb[(long)z*16777216 + (long)row*8192 + cl]        = f2b(x1*c - x2*s);
          p.Cb[(long)z*16777216 + (long)row*8192 + cl + 4096] = f2b(x2*c + x1*s);
        }
      }
    }
    return;
  }
  #pragma unroll
  for (int i = 0; i < 4; ++i){
    #pragma unroll
    for (int j = 0; j < 4; ++j){
      int col = n0 + wn*64 + j*16 + r16;
      #pragma unroll
      for (int v = 0; v < 4; ++v){
        int row = m0 + wm*64 + i*16 + s4*4 + v;
        float val = acc[i][j][v];
        if (OP==0){
          p.Cf[(long)row*256 + col] = val;
        } else if (OP==1){
          p.Cb[(long)z*16777216 + (long)row*8192 + col] = f2b(fmaxf(val,0.f));
        } else if (OP==2){
          p.Cb[(long)z*4194304 + (long)row*2048 + col] = f2b(row > col ? val : 0.f);
        } else if (OP==3){
          p.Cf[(long)z*524288 + (long)row*256 + col] = val;
        } else if (OP==5){
          long xi = (long)z*16777216 + (long)row*8192 + col;
          float xv = b2f(p.Y[xi]);
          p.Y[xi] = f2b(fmaxf(val,0.f) * xv);    // same-thread RMW, no race
        } else {  // OP==7
          p.Cf[(long)bh*524288 + (long)row*256 + col] = val;
        }
      }
    }
  }
}

// ---------------- small kernels ----------------

__device__ __forceinline__ float wave_sum(float v){
  #pragma unroll
  for (int o = 32; o > 0; o >>= 1) v += __shfl_down(v, o, 64);
  return v;
}
__device__ __forceinline__ float block_sum(float v, float* sm){
  v = wave_sum(v);
  __syncthreads();
  if ((threadIdx.x & 63) == 0) sm[threadIdx.x >> 6] = v;
  __syncthreads();
  return sm[0] + sm[1] + sm[2] + sm[3];
}

__global__ __launch_bounds__(256) void k_embed(const int* idx, const float* wte,
                                               float* v, u16* vbf, u16* vbt){
  __shared__ float sm[4];
  __shared__ int is64_s;
  int row = blockIdx.x, d = threadIdx.x;
  int oddnz = (d < 64) ? (idx[2*d + 1] != 0) : 0;     // int64 vs int32 probe
  unsigned long long mb = __ballot(oddnz);
  if (threadIdx.x == 0) is64_s = (mb == 0ULL);
  __syncthreads();
  int tok = is64_s ? idx[2*row] : idx[row];
  float x = wte[tok*256 + d];
  float m = block_sum(x, sm) * (1.f/256.f);
  float dd = x - m;
  float var = block_sum(dd*dd, sm) * (1.f/256.f);
  float y = dd * rsqrtf(var + 1e-5f);
  v[(long)row*256 + d] = y;
  vbf[(long)row*256 + d] = f2b(y);
  int b = row >> 11, t = row & 2047;
  vbt[((long)(b*256 + d))*2048 + t] = f2b(y);
}

__global__ __launch_bounds__(256) void k_ln(const float* in, u16* out){
  __shared__ float sm[4];
  long row = blockIdx.x; int d = threadIdx.x;
  float x = in[row*256 + d];
  float m = block_sum(x, sm) * (1.f/256.f);
  float dd = x - m;
  float var = block_sum(dd*dd, sm) * (1.f/256.f);
  out[row*256 + d] = f2b(dd * rsqrtf(var + 1e-5f));
}

// t1 = sum_h part[b,h]; v = ln(v + ln(t1)); refresh bf16 copies
__global__ __launch_bounds__(256) void k_finish(const float* part, float* v, u16* vbf, u16* vbt){
  __shared__ float sm[4];
  int row = blockIdx.x; int d = threadIdx.x;
  int b = row >> 11, t = row & 2047;
  long o = (long)t*256 + d;
  float s = 0.f;
  #pragma unroll
  for (int h = 0; h < 4; ++h) s += part[(long)(b*4 + h)*524288 + o];
  float m = block_sum(s, sm) * (1.f/256.f);
  float dd = s - m;
  float var = block_sum(dd*dd, sm) * (1.f/256.f);
  float u = dd * rsqrtf(var + 1e-5f);
  float wv = v[(long)row*256 + d] + u;
  float m2 = block_sum(wv, sm) * (1.f/256.f);
  float d2 = wv - m2;
  float v2 = block_sum(d2*d2, sm) * (1.f/256.f);
  float y = d2 * rsqrtf(v2 + 1e-5f);
  v[(long)row*256 + d] = y;
  vbf[(long)row*256 + d] = f2b(y);
  vbt[((long)(b*256 + d))*2048 + t] = f2b(y);
}

__global__ __launch_bounds__(256) void k_cossin(u16* ct, u16* st){
  int tid = blockIdx.x*256 + threadIdx.x;     // 2048*4096
  int t = tid >> 12, i = tid & 4095;
  float f = powf(10000.0f, -(float)i * (1.0f/4096.0f));
  float a = (float)t * f;
  float s, c; sincosf(a, &s, &c);
  ct[tid] = f2b(c); st[tid] = f2b(s);
}

// out[c][r] = bf16(in[r][c]); grid (C/32, R/32, Z), block (32,8)
__global__ void k_transpose(const float* in, u16* out, int R, int C, long in_z, long out_z){
  __shared__ float tile[32][33];
  const float* I = in + (long)blockIdx.z * in_z;
  u16* O = out + (long)blockIdx.z * out_z;
  int c0 = blockIdx.x*32, r0 = blockIdx.y*32;
  int tx = threadIdx.x, ty = threadIdx.y;
  #pragma unroll
  for (int k = 0; k < 4; ++k){ int r = ty + k*8; tile[r][tx] = I[(long)(r0+r)*C + c0+tx]; }
  __syncthreads();
  #pragma unroll
  for (int k = 0; k < 4; ++k){ int r = ty + k*8; O[(long)(c0+r)*R + r0+tx] = f2b(tile[tx][r]); }
}

// ---------------- host ----------------

extern "C" void kernel_launch(void* const* d_in, const int* in_sizes, int n_in,
                              void* d_out, int out_size, void* d_ws, size_t ws_size,
                              hipStream_t stream){
  const int*   idx = (const int*)d_in[0];
  const float* wte = (const float*)d_in[1];
  const float* enc = (const float*)d_in[2];
  const float* dx  = (const float*)d_in[3];
  const float* dy  = (const float*)d_in[4];
  const float* ro  = (const float*)d_in[5];
  float* out = (float*)d_out;
  (void)in_sizes; (void)n_in; (void)out_size;

  char* w = (char*)d_ws;
  size_t off = 0;
  auto alloc = [&](size_t b){ size_t r = off; off += (b + 255) & ~(size_t)255; return r; };
  float* v_ast = (float*)(w + alloc(4096UL*256*4));      // 4 MB
  u16*   v_bf  = (u16*)  (w + alloc(4096UL*256*2));      // 2 MB
  u16*   v_bt  = (u16*)  (w + alloc(2UL*256*2048*2));    // 2 MB (b,d,t)
  u16*   dxT   = (u16*)  (w + alloc(4UL*8192*256*2));    // 16 MB
  u16*   dyT   = (u16*)  (w + alloc(4UL*8192*256*2));    // 16 MB
  u16*   encT  = (u16*)  (w + alloc(256UL*32768*2));     // 16 MB
  u16*   roT   = (u16*)  (w + alloc(256UL*256*2));
  u16*   ct    = (u16*)  (w + alloc(2048UL*4096*2));     // 16 MB
  u16*   st    = (u16*)  (w + alloc(2048UL*4096*2));     // 16 MB
  float* part  = (float*)(w + alloc(8UL*2048*256*4));    // 16 MB
  long avail = (long)ws_size - (long)off;
  int gc = 8;
  while (gc > 1 && (long)gc*45088768L > avail) gc >>= 1;  // 43 MB per head
  u16*   xbuf  = (u16*)  (w + alloc((size_t)gc*33554432)); // xr, then x/y (32 MB/head)
  u16*   scb   = (u16*)  (w + alloc((size_t)gc*8388608));  // scores (8 MB/head)
  float* abuf  = (float*)(w + alloc((size_t)gc*2097152));  // attn out (2 MB/head)
  u16*   lnAb  = (u16*)  (w + alloc((size_t)gc*1048576));  // ln(a) bf16 (1 MB/head)

  dim3 tb(32, 8);
  k_cossin<<<32768, 256, 0, stream>>>(ct, st);
  k_transpose<<<dim3(256, 8, 4),  tb, 0, stream>>>(dx,  dxT,  256,   8192, 256L*8192, 8192L*256);
  k_transpose<<<dim3(256, 8, 4),  tb, 0, stream>>>(dy,  dyT,  256,   8192, 256L*8192, 8192L*256);
  k_transpose<<<dim3(8, 1024, 1), tb, 0, stream>>>(enc, encT, 32768, 256,  0, 0);
  k_transpose<<<dim3(8, 8, 1),    tb, 0, stream>>>(ro,  roT,  256,   256,  0, 0);
  k_embed<<<4096, 256, 0, stream>>>(idx, wte, v_ast, v_bf, v_bt);

  for (int l = 0; l < 6; ++l){
    for (int bh0 = 0; bh0 < 8; bh0 += gc){
      { GP g{}; g.bh0=bh0; g.ct=ct; g.st=st; g.A=v_bf; g.Bt=dxT; g.Cb=xbuf;   // G1+rope -> xr
        gemm<6><<<dim3(64,16,gc), 256, 0, stream>>>(g); }
      { GP g{}; g.bh0=bh0; g.A=xbuf; g.Cb=scb;                                 // QK -> sc
        gemm<2><<<dim3(16,16,gc), 256, 0, stream>>>(g); }
      { GP g{}; g.bh0=bh0; g.A=scb; g.Bt=v_bt; g.Cf=abuf;                      // PV -> a
        gemm<3><<<dim3(2,16,gc), 256, 0, stream>>>(g); }
      k_ln<<<gc*2048, 256, 0, stream>>>(abuf, lnAb);                           // ln(a)
      { GP g{}; g.bh0=bh0; g.A=v_bf; g.Bt=dxT; g.Cb=xbuf;                      // recompute x
        gemm<1><<<dim3(64,16,gc), 256, 0, stream>>>(g); }
      { GP g{}; g.bh0=bh0; g.A=lnAb; g.Bt=dyT; g.Y=xbuf;                       // y = relu(.)*x
        gemm<5><<<dim3(64,16,gc), 256, 0, stream>>>(g); }
      { GP g{}; g.bh0=bh0; g.A=xbuf; g.Bt=encT; g.Cf=part;                     // part[bh] = y@enc
        gemm<7><<<dim3(2,16,gc), 256, 0, stream>>>(g); }
    }
    k_finish<<<4096, 256, 0, stream>>>(part, v_ast, v_bf, v_bt);
  }
  { GP g{}; g.A=v_bf; g.Bt=roT; g.Cf=out;                                      // readout
    gemm<0><<<dim3(2,32,1), 256, 0, stream>>>(g); }
}

// Round 5
// 7835.167 us; speedup vs baseline: 1.5600x; 1.5600x over previous
//
#include <hip/hip_runtime.h>
#include <stdint.h>

// BDH: B=2 T=2048 D=256 H=4 N=32768 Nh=8192 L=6 VOCAB=256
typedef unsigned short u16;
typedef __bf16 bfv8 __attribute__((ext_vector_type(8)));
typedef float f32x4 __attribute__((ext_vector_type(4)));

#define BM 128
#define BN 128
#define BK 32

__device__ __forceinline__ float b2f(u16 u){ union{float f; unsigned int i;} x; x.i = ((unsigned int)u)<<16; return x.f; }
__device__ __forceinline__ u16 f2b(float f){ union{float f; unsigned int i;} x; x.f = f; unsigned int r = x.i + 0x7fffu + ((x.i>>16)&1u); return (u16)(r>>16); }

__device__ __forceinline__ void load16_lds(const void* g, void* l){
  __builtin_amdgcn_global_load_lds(
      (const __attribute__((address_space(1))) void*)g,
      (__attribute__((address_space(3))) void*)l, 16, 0, 0);
}

// bijective XCD-aware block remap (m204), then decompose
__device__ __forceinline__ void swz(int& bx, int& by, int& bz){
  int gx = gridDim.x, gy = gridDim.y;
  int nw = gx*gy*gridDim.z;
  int flat = blockIdx.x + gx*(blockIdx.y + gy*blockIdx.z);
  int q = nw >> 3, r = nw & 7, xcd = flat & 7, i = flat >> 3;
  int wg = (xcd < r ? xcd*(q+1) : r*(q+1) + (xcd-r)*q) + i;
  bx = wg % gx; int t = wg / gx; by = t % gy; bz = t / gy;
}

struct GP {
  const u16* A; const u16* Bt; const u16* A2; const u16* Bt2;
  const u16* ct; const u16* st;
  float* Cf; u16* Cb; u16* Y;
  int bh0, zs, zm;
};

// shared K-loop: A(MxK,lda) x Bt(NxK,ldb)^T accumulated into acc[4][4]
template<int LDA, int LDB, bool PAIRB>
__device__ __forceinline__ void kloop(const u16* A, const u16* Bt, int m0, int n0,
                                      int kbeg, int kend, u16* As, u16* Bs,
                                      f32x4 (&acc)[4][4]){
  const int tid = threadIdx.x;
  const int lane = tid & 63;
  const int wid = tid >> 6;
  const int wm = wid >> 1, wn = wid & 1;
  const int srow = tid >> 2, sslot = tid & 3;
  for (int k0 = kbeg; k0 < kend; k0 += BK){
    #pragma unroll
    for (int q = 0; q < 2; ++q){
      int row = q*64 + srow;
      int ks = sslot ^ ((row >> 1) & 3);           // bank-spread XOR swizzle
      load16_lds(A + (long)(m0 + row)*LDA + (k0 + ks*8), As + q*2048 + wid*512);
    }
    #pragma unroll
    for (int q = 0; q < 2; ++q){
      int row = q*64 + srow;
      int ks = sslot ^ ((row >> 1) & 3);
      long brow;
      if (PAIRB){ int wnb = row >> 6, sub = (row >> 5) & 1, r5 = row & 31;
                  brow = n0 + wnb*32 + r5 + sub*4096; }
      else brow = n0 + row;
      load16_lds(Bt + brow*(long)LDB + (k0 + ks*8), Bs + q*2048 + wid*512);
    }
    __syncthreads();
    bfv8 af[4], bf[4];
    const int r16 = lane & 15, s4 = lane >> 4;
    #pragma unroll
    for (int i = 0; i < 4; ++i){
      int ar = wm*64 + i*16 + r16;
      af[i] = *(const bfv8*)(As + ar*BK + ((s4 ^ ((ar>>1)&3))*8));
      int br = wn*64 + i*16 + r16;
      bf[i] = *(const bfv8*)(Bs + br*BK + ((s4 ^ ((br>>1)&3))*8));
    }
    #pragma unroll
    for (int i = 0; i < 4; ++i)
      #pragma unroll
      for (int j = 0; j < 4; ++j)
        acc[i][j] = __builtin_amdgcn_mfma_f32_16x16x32_bf16(af[i], bf[j], acc[i][j], 0,0,0);
    __syncthreads();
  }
}

#define EPI_SETUP const int lane = threadIdx.x & 63, wid = threadIdx.x >> 6; \
  const int wm = wid >> 1, wn = wid & 1; const int r16 = lane & 15, s4 = lane >> 4;

// G1+rope: xr = rope(relu(v @ dx_h))  -> Cb[z] (2048 x 8192)
__global__ __launch_bounds__(256) void g_rope(GP p){
  int bx, by, bz; swz(bx, by, bz);
  const int m0 = by*BM, n0 = bx*64, z = bz;
  const int bh = p.bh0 + z, b = bh >> 2, h = bh & 3;
  __shared__ u16 As[BM*BK], Bs[BN*BK];
  f32x4 acc[4][4] = {};
  kloop<256,256,true>(p.A + (long)b*524288, p.Bt + (long)h*2097152, m0, n0, 0, 256, As, Bs, acc);
  EPI_SETUP
  #pragma unroll
  for (int i = 0; i < 4; ++i)
    #pragma unroll
    for (int j = 0; j < 2; ++j){
      int cl = n0 + wn*32 + j*16 + r16;
      #pragma unroll
      for (int v = 0; v < 4; ++v){
        int row = m0 + wm*64 + i*16 + s4*4 + v;
        float x1 = fmaxf(acc[i][j][v], 0.f);
        float x2 = fmaxf(acc[i][j+2][v], 0.f);
        float c = b2f(p.ct[(long)row*4096 + cl]);
        float s = b2f(p.st[(long)row*4096 + cl]);
        p.Cb[(long)z*16777216 + (long)row*8192 + cl]        = f2b(x1*c - x2*s);
        p.Cb[(long)z*16777216 + (long)row*8192 + cl + 4096] = f2b(x2*c + x1*s);
      }
    }
}

// QK: sc[z] = causal_mask(xr[z] @ xr[z]^T)
__global__ __launch_bounds__(256) void g_qk(GP p){
  int bx, by, bz; swz(bx, by, bz);
  const int m0 = by*BM, n0 = bx*BN, z = bz;
  if (n0 >= m0 + BM) return;
  __shared__ u16 As[BM*BK], Bs[BN*BK];
  f32x4 acc[4][4] = {};
  const u16* A = p.A + (long)z*16777216;
  kloop<8192,8192,false>(A, A, m0, n0, 0, 8192, As, Bs, acc);
  EPI_SETUP
  #pragma unroll
  for (int i = 0; i < 4; ++i)
    #pragma unroll
    for (int j = 0; j < 4; ++j){
      int col = n0 + wn*64 + j*16 + r16;
      #pragma unroll
      for (int v = 0; v < 4; ++v){
        int row = m0 + wm*64 + i*16 + s4*4 + v;
        p.Cb[(long)z*4194304 + (long)row*2048 + col] = f2b(row > col ? acc[i][j][v] : 0.f);
      }
    }
}

// PV split-K: abuf[z] = sc[head] @ v_bt[b]  (k in [sl*kc, min(m0+128, (sl+1)*kc)))
__global__ __launch_bounds__(256) void g_pv(GP p){
  int bx, by, bz; swz(bx, by, bz);
  const int m0 = by*BM, n0 = bx*BN;
  const int head = bz >> p.zs, sl = bz & p.zm;
  const int b = (p.bh0 + head) >> 2;
  const int kc = 2048 >> p.zs;
  const int kbeg = sl*kc;
  const int kend = min(min(2048, m0 + BM), kbeg + kc);
  __shared__ u16 As[BM*BK], Bs[BN*BK];
  f32x4 acc[4][4] = {};
  kloop<2048,2048,false>(p.A + (long)head*4194304, p.Bt + (long)b*524288, m0, n0, kbeg, kend, As, Bs, acc);
  EPI_SETUP
  #pragma unroll
  for (int i = 0; i < 4; ++i)
    #pragma unroll
    for (int j = 0; j < 4; ++j){
      int col = n0 + wn*64 + j*16 + r16;
      #pragma unroll
      for (int v = 0; v < 4; ++v){
        int row = m0 + wm*64 + i*16 + s4*4 + v;
        p.Cf[(long)bz*524288 + (long)row*256 + col] = acc[i][j][v];
      }
    }
}

// fused y: Y[z] = relu(lnA[z] @ dyT_h) * relu(v[b] @ dxT_h)
__global__ __launch_bounds__(256) void g_fuse(GP p){
  int bx, by, bz; swz(bx, by, bz);
  const int m0 = by*BM, n0 = bx*BN, z = bz;
  const int bh = p.bh0 + z, b = bh >> 2, h = bh & 3;
  __shared__ u16 As[BM*BK], Bs[BN*BK];
  f32x4 acc1[4][4] = {}, acc2[4][4] = {};
  kloop<256,256,false>(p.A  + (long)z*524288, p.Bt  + (long)h*2097152, m0, n0, 0, 256, As, Bs, acc1);
  kloop<256,256,false>(p.A2 + (long)b*524288, p.Bt2 + (long)h*2097152, m0, n0, 0, 256, As, Bs, acc2);
  EPI_SETUP
  #pragma unroll
  for (int i = 0; i < 4; ++i)
    #pragma unroll
    for (int j = 0; j < 4; ++j){
      int col = n0 + wn*64 + j*16 + r16;
      #pragma unroll
      for (int v = 0; v < 4; ++v){
        int row = m0 + wm*64 + i*16 + s4*4 + v;
        p.Y[(long)z*16777216 + (long)row*8192 + col] =
            f2b(fmaxf(acc1[i][j][v], 0.f) * fmaxf(acc2[i][j][v], 0.f));
      }
    }
}

// G3 split-K: part[z] = y[head] @ encT_h  (k chunk sp)
__global__ __launch_bounds__(256) void g_enc(GP p){
  int bx, by, bz; swz(bx, by, bz);
  const int m0 = by*BM, n0 = bx*BN;
  const int head = bz >> p.zs, sp = bz & p.zm;
  const int h = (p.bh0 + head) & 3;
  const int kc = 8192 >> p.zs;
  const int kbeg = sp*kc, kend = kbeg + kc;
  __shared__ u16 As[BM*BK], Bs[BN*BK];
  f32x4 acc[4][4] = {};
  kloop<8192,32768,false>(p.A + (long)head*16777216, p.Bt + (long)h*8192, m0, n0, kbeg, kend, As, Bs, acc);
  EPI_SETUP
  #pragma unroll
  for (int i = 0; i < 4; ++i)
    #pragma unroll
    for (int j = 0; j < 4; ++j){
      int col = n0 + wn*64 + j*16 + r16;
      #pragma unroll
      for (int v = 0; v < 4; ++v){
        int row = m0 + wm*64 + i*16 + s4*4 + v;
        p.Cf[(long)bz*524288 + (long)row*256 + col] = acc[i][j][v];
      }
    }
}

// readout: out = v_bf @ roT^T (f32)
__global__ __launch_bounds__(256) void g_out(GP p){
  int bx, by, bz; swz(bx, by, bz); (void)bz;
  const int m0 = by*BM, n0 = bx*BN;
  __shared__ u16 As[BM*BK], Bs[BN*BK];
  f32x4 acc[4][4] = {};
  kloop<256,256,false>(p.A, p.Bt, m0, n0, 0, 256, As, Bs, acc);
  EPI_SETUP
  #pragma unroll
  for (int i = 0; i < 4; ++i)
    #pragma unroll
    for (int j = 0; j < 4; ++j){
      int col = n0 + wn*64 + j*16 + r16;
      #pragma unroll
      for (int v = 0; v < 4; ++v){
        int row = m0 + wm*64 + i*16 + s4*4 + v;
        p.Cf[(long)row*256 + col] = acc[i][j][v];
      }
    }
}

// ---------------- small kernels ----------------

__device__ __forceinline__ float wave_sum(float v){
  #pragma unroll
  for (int o = 32; o > 0; o >>= 1) v += __shfl_down(v, o, 64);
  return v;
}
__device__ __forceinline__ float block_sum(float v, float* sm){
  v = wave_sum(v);
  __syncthreads();
  if ((threadIdx.x & 63) == 0) sm[threadIdx.x >> 6] = v;
  __syncthreads();
  return sm[0] + sm[1] + sm[2] + sm[3];
}

__global__ __launch_bounds__(256) void k_embed(const int* idx, const float* wte,
                                               float* v, u16* vbf, u16* vbt){
  __shared__ float sm[4];
  __shared__ int is64_s;
  int row = blockIdx.x, d = threadIdx.x;
  int oddnz = (d < 64) ? (idx[2*d + 1] != 0) : 0;     // int64 vs int32 probe
  unsigned long long mb = __ballot(oddnz);
  if (threadIdx.x == 0) is64_s = (mb == 0ULL);
  __syncthreads();
  int tok = is64_s ? idx[2*row] : idx[row];
  float x = wte[tok*256 + d];
  float m = block_sum(x, sm) * (1.f/256.f);
  float dd = x - m;
  float var = block_sum(dd*dd, sm) * (1.f/256.f);
  float y = dd * rsqrtf(var + 1e-5f);
  v[(long)row*256 + d] = y;
  vbf[(long)row*256 + d] = f2b(y);
  int b = row >> 11, t = row & 2047;
  vbt[((long)(b*256 + d))*2048 + t] = f2b(y);
}

// sum pv slices of abuf, LN -> lnA (bf16)
__global__ __launch_bounds__(256) void k_ln(const float* abuf, u16* out, int pv){
  __shared__ float sm[4];
  int row = blockIdx.x, d = threadIdx.x;
  int head = row >> 11, t = row & 2047;
  float x = 0.f;
  for (int s = 0; s < pv; ++s) x += abuf[((long)(head*pv + s) << 19) + (long)t*256 + d];
  float m = block_sum(x, sm) * (1.f/256.f);
  float dd = x - m;
  float var = block_sum(dd*dd, sm) * (1.f/256.f);
  out[(long)row*256 + d] = f2b(dd * rsqrtf(var + 1e-5f));
}

// t1[b] (init or +=) sum over this chunk's heads/splits of part
__global__ __launch_bounds__(256) void k_acc(const float* part, float* t1,
                                             int bh0, int gc, int ps){
  int t = blockIdx.x, d = threadIdx.x;
  long o = (long)t*256 + d;
  float s0 = 0.f, s1 = 0.f;
  for (int z = 0; z < gc; ++z){
    float v = 0.f;
    for (int sp = 0; sp < ps; ++sp) v += part[((long)(z*ps + sp) << 19) + o];
    if (((bh0 + z) >> 2) == 0) s0 += v; else s1 += v;
  }
  // interval overlap [bh0, bh0+gc) vs [4b, 4b+4): init if chunk contains 4b, else accumulate
  #pragma unroll
  for (int b = 0; b < 2; ++b){
    int lo = bh0 > 4*b ? bh0 : 4*b;
    int hi = (bh0 + gc) < (4*b + 4) ? (bh0 + gc) : (4*b + 4);
    if (lo < hi){
      float s = b == 0 ? s0 : s1;
      if (lo == 4*b) t1[((long)b << 19) + o] = s;
      else           t1[((long)b << 19) + o] += s;
    }
  }
}

// v = ln(v + ln(t1)); refresh bf16 copies
__global__ __launch_bounds__(256) void k_finish(const float* t1, float* v, u16* vbf, u16* vbt){
  __shared__ float sm[4];
  int row = blockIdx.x; int d = threadIdx.x;
  int b = row >> 11, t = row & 2047;
  float s = t1[(long)row*256 + d];
  float m = block_sum(s, sm) * (1.f/256.f);
  float dd = s - m;
  float var = block_sum(dd*dd, sm) * (1.f/256.f);
  float u = dd * rsqrtf(var + 1e-5f);
  float wv = v[(long)row*256 + d] + u;
  float m2 = block_sum(wv, sm) * (1.f/256.f);
  float d2 = wv - m2;
  float v2 = block_sum(d2*d2, sm) * (1.f/256.f);
  float y = d2 * rsqrtf(v2 + 1e-5f);
  v[(long)row*256 + d] = y;
  vbf[(long)row*256 + d] = f2b(y);
  vbt[((long)(b*256 + d))*2048 + t] = f2b(y);
}

__global__ __launch_bounds__(256) void k_cossin(u16* ct, u16* st){
  int tid = blockIdx.x*256 + threadIdx.x;     // 2048*4096
  int t = tid >> 12, i = tid & 4095;
  float f = powf(10000.0f, -(float)i * (1.0f/4096.0f));
  float a = (float)t * f;
  float s, c; sincosf(a, &s, &c);
  ct[tid] = f2b(c); st[tid] = f2b(s);
}

// out[c][r] = bf16(in[r][c]); grid (C/32, R/32, Z), block (32,8)
__global__ void k_transpose(const float* in, u16* out, int R, int C, long in_z, long out_z){
  __shared__ float tile[32][33];
  const float* I = in + (long)blockIdx.z * in_z;
  u16* O = out + (long)blockIdx.z * out_z;
  int c0 = blockIdx.x*32, r0 = blockIdx.y*32;
  int tx = threadIdx.x, ty = threadIdx.y;
  #pragma unroll
  for (int k = 0; k < 4; ++k){ int r = ty + k*8; tile[r][tx] = I[(long)(r0+r)*C + c0+tx]; }
  __syncthreads();
  #pragma unroll
  for (int k = 0; k < 4; ++k){ int r = ty + k*8; O[(long)(c0+r)*R + r0+tx] = f2b(tile[tx][r]); }
}

// ---------------- host ----------------

extern "C" void kernel_launch(void* const* d_in, const int* in_sizes, int n_in,
                              void* d_out, int out_size, void* d_ws, size_t ws_size,
                              hipStream_t stream){
  const int*   idx = (const int*)d_in[0];
  const float* wte = (const float*)d_in[1];
  const float* enc = (const float*)d_in[2];
  const float* dx  = (const float*)d_in[3];
  const float* dy  = (const float*)d_in[4];
  const float* ro  = (const float*)d_in[5];
  float* out = (float*)d_out;
  (void)in_sizes; (void)n_in; (void)out_size;

  // config ladder: gc heads/chunk, pv PV-splits, ps G3-splits
  const size_t base_b = 96600064UL;
  struct Cfg { int gc, pvs, pss; };
  const Cfg lad[] = {{8,2,3},{4,2,3},{2,2,3},{2,1,2},{1,2,3},{1,1,2},{1,0,1},{1,0,0}};
  Cfg cfg = lad[7];
  for (int i = 0; i < 8; ++i){
    size_t ch = (size_t)lad[i].gc * (33554432UL + 8388608UL + 1048576UL
               + ((size_t)(1 << lad[i].pvs))*2097152UL
               + ((size_t)(1 << lad[i].pss))*2097152UL);
    if (base_b + ch <= ws_size){ cfg = lad[i]; break; }
  }
  const int gc = cfg.gc, pvs = cfg.pvs, pss = cfg.pss;
  const int pv = 1 << pvs, ps = 1 << pss;

  char* w = (char*)d_ws;
  size_t off = 0;
  auto alloc = [&](size_t b){ size_t r = off; off += (b + 255) & ~(size_t)255; return r; };
  float* v_ast = (float*)(w + alloc(4096UL*256*4));
  u16*   v_bf  = (u16*)  (w + alloc(4096UL*256*2));
  u16*   v_bt  = (u16*)  (w + alloc(2UL*256*2048*2));
  u16*   dxT   = (u16*)  (w + alloc(4UL*8192*256*2));
  u16*   dyT   = (u16*)  (w + alloc(4UL*8192*256*2));
  u16*   encT  = (u16*)  (w + alloc(256UL*32768*2));
  u16*   roT   = (u16*)  (w + alloc(256UL*256*2));
  u16*   ct    = (u16*)  (w + alloc(2048UL*4096*2));
  u16*   st    = (u16*)  (w + alloc(2048UL*4096*2));
  float* t1    = (float*)(w + alloc(2UL*2048*256*4));
  u16*   xbuf  = (u16*)  (w + alloc((size_t)gc*33554432));
  u16*   scb   = (u16*)  (w + alloc((size_t)gc*8388608));
  u16*   lnAb  = (u16*)  (w + alloc((size_t)gc*1048576));
  float* abuf  = (float*)(w + alloc((size_t)gc*pv*2097152UL));
  float* part  = (float*)(w + alloc((size_t)gc*ps*2097152UL));

  dim3 tb(32, 8);
  k_cossin<<<32768, 256, 0, stream>>>(ct, st);
  k_transpose<<<dim3(256, 8, 4),  tb, 0, stream>>>(dx,  dxT,  256,   8192, 256L*8192, 8192L*256);
  k_transpose<<<dim3(256, 8, 4),  tb, 0, stream>>>(dy,  dyT,  256,   8192, 256L*8192, 8192L*256);
  k_transpose<<<dim3(8, 1024, 1), tb, 0, stream>>>(enc, encT, 32768, 256,  0, 0);
  k_transpose<<<dim3(8, 8, 1),    tb, 0, stream>>>(ro,  roT,  256,   256,  0, 0);
  k_embed<<<4096, 256, 0, stream>>>(idx, wte, v_ast, v_bf, v_bt);

  for (int l = 0; l < 6; ++l){
    for (int bh0 = 0; bh0 < 8; bh0 += gc){
      { GP g{}; g.bh0=bh0; g.A=v_bf; g.Bt=dxT; g.ct=ct; g.st=st; g.Cb=xbuf;
        g_rope<<<dim3(64,16,gc), 256, 0, stream>>>(g); }
      { GP g{}; g.bh0=bh0; g.A=xbuf; g.Cb=scb;
        g_qk<<<dim3(16,16,gc), 256, 0, stream>>>(g); }
      { GP g{}; g.bh0=bh0; g.A=scb; g.Bt=v_bt; g.Cf=abuf; g.zs=pvs; g.zm=pv-1;
        g_pv<<<dim3(2,16,gc*pv), 256, 0, stream>>>(g); }
      k_ln<<<gc*2048, 256, 0, stream>>>(abuf, lnAb, pv);
      { GP g{}; g.bh0=bh0; g.A=lnAb; g.Bt=dyT; g.A2=v_bf; g.Bt2=dxT; g.Y=xbuf;
        g_fuse<<<dim3(64,16,gc), 256, 0, stream>>>(g); }
      { GP g{}; g.bh0=bh0; g.A=xbuf; g.Bt=encT; g.Cf=part; g.zs=pss; g.zm=ps-1;
        g_enc<<<dim3(2,16,gc*ps), 256, 0, stream>>>(g); }
      k_acc<<<2048, 256, 0, stream>>>(part, t1, bh0, gc, ps);
    }
    k_finish<<<4096, 256, 0, stream>>>(t1, v_ast, v_bf, v_bt);
  }
  { GP g{}; g.A=v_bf; g.Bt=roT; g.Cf=out;
    g_out<<<dim3(2,32,1), 256, 0, stream>>>(g); }
}